// Round 8
// baseline (393.607 us; speedup 1.0000x reference)
//
#include <hip/hip_runtime.h>
#include <math.h>

#define NX   160
#define N2   25600        // 160*160
#define N3   4096000      // 160^3
#define NB   4

#define NBLK_S 2048       // sums kernel: 512 blocks per batch
#define SBLK_PER_B 512
#define F4_PER_BLK 2000   // 1024000 float4 per batch / 512 blocks

#define XT   8            // f4 columns per fused tile (32 x)
#define YT   32           // y rows per fused tile
#define ZCH  10           // z outputs per block (half an XCD slab)
#define SROWS 40          // YT + 8 (y halo)
#define NBLK_F 1600       // 8 xcd * (5 xt * 5 yt * 2 zs * 4 b)

// 1D Gaussian taps exp(-d^2/50), d=-4..4 (NOT normalized, matches reference)
__device__ __constant__ float G1[9] = {
    0.72614903f, 0.83527021f, 0.92311635f, 0.98019867f, 1.0f,
    0.98019867f, 0.92311635f, 0.83527021f, 0.72614903f};

// edge sums: FULL - missing taps at low/high boundary
#define ES_FULL 7.92946852f
__device__ __constant__ float ES_M[4] = {3.46473426f, 2.48453559f, 1.56141924f,
                                         0.72614903f};
__device__ inline float edge_sum(int i) {
    float s = ES_FULL;
    if (i < 4) s -= ES_M[i];
    if (i > NX - 5) s -= ES_M[NX - 1 - i];
    return s;
}

__device__ inline float4 f4_zero() { return make_float4(0.f, 0.f, 0.f, 0.f); }
__device__ inline float4 f4_axpy(float a, float4 b, float4 c) {
    return make_float4(c.x + a * b.x, c.y + a * b.y, c.z + a * b.z, c.w + a * b.w);
}

// block = 256 threads (4 waves). Reduce NV doubles, plain store.
template <int NV>
__device__ inline void block_reduce_store(double* vals, double* dst) {
    __shared__ double red[4][NV];
    int lane = threadIdx.x & 63;
    int wave = threadIdx.x >> 6;
#pragma unroll
    for (int v = 0; v < NV; ++v) {
        double x = vals[v];
#pragma unroll
        for (int off = 32; off > 0; off >>= 1) x += __shfl_down(x, off, 64);
        if (lane == 0) red[wave][v] = x;
    }
    __syncthreads();
    if (threadIdx.x < NV) {
        int v = threadIdx.x;
        dst[v] = red[0][v] + red[1][v] + red[2][v] + red[3][v];
    }
}

// Pure streaming per-batch sums (verified R7). Coalesced float4.
__global__ __launch_bounds__(256) void sums_kernel(
    const float* __restrict__ labels, const float* __restrict__ inputs,
    double* __restrict__ pS) {
    int blk = blockIdx.x;
    int b = blk >> 9;          // 0..3
    int chunk = blk & 511;
    const float4* lp = (const float4*)(labels + b * N3) + chunk * F4_PER_BLK;
    const float4* ip = (const float4*)(inputs + b * N3) + chunk * F4_PER_BLK;
    double sp = 0.0, sip = 0.0, si = 0.0;
    for (int i = threadIdx.x; i < F4_PER_BLK; i += 256) {
        float4 p = lp[i];
        float4 in = ip[i];
        sp += (double)(p.x + p.y + p.z + p.w);
        sip += (double)(in.x * p.x + in.y * p.y + in.z * p.z + in.w * p.w);
        si += (double)(in.x + in.y + in.z + in.w);
    }
    double vals[3] = {sp, sip, si};
    block_reduce_store<3>(vals, pS + 3 * blk);
}

// R11: fused conv with LDS-shared xconv. Block tile = XT f4-cols x YT rows,
// slides z over ZCH planes. Per plane: stage x-conv rows (y-halo) into
// ping-pong LDS ONCE (amp 2.24x vs R10's 9x private recompute), each thread
// y-dots 9 LDS rows -> win[9] register z-window -> z-dot -> pointwise.
// One __syncthreads per plane (ping-pong WAR protected by next iter barrier).
// Slab-mapped: xcd = bid&7 owns z in [20*xcd, 20*xcd+20).
__global__ __launch_bounds__(256) void fused_conv_kernel(
    const float* __restrict__ labels, const float* __restrict__ inputs,
    const double* __restrict__ pS, double* __restrict__ pZ) {
    int tid = threadIdx.x;
    int xcd = blockIdx.x & 7;
    int u = blockIdx.x >> 3;      // 0..199
    int xt = u % 5;
    int yt = (u / 5) % 5;
    int zs = (u / 25) % 2;
    int b = u / 50;               // 0..3, uniform per block
    int x0f = xt * XT;            // f4 col base
    int y0 = yt * YT;
    int z0 = xcd * 20 + zs * ZCH;

    // ---- fused S reduce (verified R7/R10 pattern) ----
    __shared__ float sM[2];
    {
        double v0 = 0, v1 = 0, v2 = 0;
        for (int i = tid; i < SBLK_PER_B; i += 256) {
            const double* p = pS + 3 * (SBLK_PER_B * b + i);
            v0 += p[0]; v1 += p[1]; v2 += p[2];
        }
        __shared__ double red[4][3];
        int lane = tid & 63, wave = tid >> 6;
        double vals[3] = {v0, v1, v2};
#pragma unroll
        for (int v = 0; v < 3; ++v) {
            double x = vals[v];
#pragma unroll
            for (int off = 32; off > 0; off >>= 1) x += __shfl_down(x, off, 64);
            if (lane == 0) red[wave][v] = x;
        }
        __syncthreads();
        if (tid == 0) {
            double sp = red[0][0] + red[1][0] + red[2][0] + red[3][0];
            double sip = red[0][1] + red[1][1] + red[2][1] + red[3][1];
            double si = red[0][2] + red[1][2] + red[2][2] + red[3][2];
            const double Nv = (double)N3;
            sM[0] = (float)((sip / Nv) / (sp / Nv + 1e-5));
            sM[1] = (float)(((si - sip) / Nv) / ((Nv - sp) / Nv + 1e-5));
        }
        __syncthreads();
    }
    float m0 = sM[0], m1 = sM[1];

    // output coords for this thread
    int ox = tid & 7;             // f4 col within tile
    int oy = tid >> 3;            // y row within tile, 0..31
    int x4o = x0f + ox;
    int y = y0 + oy;
    int xo = x4o * 4;
    float ey = edge_sum(y);
    float cx[4] = {edge_sum(xo) * ey, edge_sum(xo + 1) * ey,
                   edge_sum(xo + 2) * ey, edge_sum(xo + 3) * ey};

    const float* lbase = labels + b * N3;
    const float* ibase = inputs + b * N3;
    int po = y * NX + xo;         // in-plane offset of this thread's output

    __shared__ float4 sbuf[2][SROWS][XT];

    float4 win[9];
    float n0 = 0.f, d0 = 0.f, n1 = 0.f, d1 = 0.f;

    // 18 iterations: stage planes z0-4 .. z0+13; outputs at k=8..17.
    for (int k = 0; k < ZCH + 8; ++k) {
        int zp = z0 - 4 + k;
        float4* dst = &sbuf[k & 1][0][0];
        if (zp >= 0 && zp < NX) {
            const float* pl = lbase + zp * N2;
#pragma unroll
            for (int s0 = 0; s0 < SROWS * XT; s0 += 256) {
                int s = s0 + tid;
                if (s < SROWS * XT) {
                    int sc = s & 7;           // f4 col in tile
                    int sr = s >> 3;          // staged row
                    int gy = y0 - 4 + sr;
                    int gc = x0f + sc;        // global f4 col of xconv output
                    float4 o = f4_zero();
                    if (gy >= 0 && gy < NX) {
                        const float* row = pl + gy * NX;
                        float w[12];
#pragma unroll
                        for (int c = 0; c < 3; ++c) {
                            int g4 = gc - 1 + c;
                            float4 v = (g4 >= 0 && g4 < 40)
                                           ? *(const float4*)&row[4 * g4]
                                           : f4_zero();
                            w[4 * c] = v.x; w[4 * c + 1] = v.y;
                            w[4 * c + 2] = v.z; w[4 * c + 3] = v.w;
                        }
#pragma unroll
                        for (int kk = 0; kk < 9; ++kk) {
                            float g = G1[kk];
                            o.x += g * w[kk];     o.y += g * w[kk + 1];
                            o.z += g * w[kk + 2]; o.w += g * w[kk + 3];
                        }
                    }
                    dst[s] = o;
                }
            }
        } else {
#pragma unroll
            for (int s0 = 0; s0 < SROWS * XT; s0 += 256) {
                int s = s0 + tid;
                if (s < SROWS * XT) dst[s] = f4_zero();
            }
        }
        __syncthreads();

        // y-dot of plane zp from LDS
        float4 w8 = f4_zero();
#pragma unroll
        for (int dy = 0; dy < 9; ++dy)
            w8 = f4_axpy(G1[dy], sbuf[k & 1][oy + dy][ox], w8);

        if (k < 8) {
            win[k] = w8;
        } else {
            if (k > 8) {
#pragma unroll
                for (int d = 0; d < 8; ++d) win[d] = win[d + 1];
            }
            win[8] = w8;
            int z = z0 + k - 8;
            float4 pv = *(const float4*)&lbase[z * N2 + po];
            float4 iv = *(const float4*)&ibase[z * N2 + po];
            float4 c4 = f4_zero();
#pragma unroll
            for (int d = 0; d < 9; ++d) c4 = f4_axpy(G1[d], win[d], c4);
            float ez = edge_sum(z);
            float pc[4] = {pv.x, pv.y, pv.z, pv.w};
            float ic[4] = {iv.x, iv.y, iv.z, iv.w};
            float cc[4] = {c4.x, c4.y, c4.z, c4.w};
#pragma unroll
            for (int l = 0; l < 4; ++l) {
                float c1 = cx[l] * ez - cc[l];  // conv(1-p) via conv(ones)
                float df0 = ic[l] - m0; df0 *= df0;
                float w0 = __expf(-df0 * df0);
                float df1 = ic[l] - m1; df1 *= df1;
                float w1 = __expf(-df1 * df1);
                n0 += cc[l] * pc[l] * w0;
                d0 += cc[l] * w0;
                n1 += c1 * (1.f - pc[l]) * w1;
                d1 += c1 * w1;
            }
        }
        __syncthreads();   // protect sbuf[k&1] reuse at iter k+2
    }
    double vals[4] = {(double)n0, (double)d0, (double)n1, (double)d1};
    block_reduce_store<4>(vals, pZ + 4 * blockIdx.x);
}

// single block: sum 1600 per-block partials, compute final loss
__global__ __launch_bounds__(256) void finalize_kernel(
    const double* __restrict__ pZ, float* __restrict__ out) {
    double a0 = 0, a1 = 0, a2 = 0, a3 = 0;
    for (int i = threadIdx.x; i < NBLK_F; i += 256) {
        const double* p = &pZ[4 * i];
        a0 += p[0]; a1 += p[1]; a2 += p[2]; a3 += p[3];
    }
    __shared__ double red[4][4];
    int lane = threadIdx.x & 63;
    int wave = threadIdx.x >> 6;
    double vals[4] = {a0, a1, a2, a3};
#pragma unroll
    for (int v = 0; v < 4; ++v) {
        double x = vals[v];
#pragma unroll
        for (int off = 32; off > 0; off >>= 1) x += __shfl_down(x, off, 64);
        if (lane == 0) red[wave][v] = x;
    }
    __syncthreads();
    if (threadIdx.x == 0) {
        double acc[4];
#pragma unroll
        for (int v = 0; v < 4; ++v)
            acc[v] = red[0][v] + red[1][v] + red[2][v] + red[3][v];
        double r0 = fabs(acc[0] / (acc[1] + 1e-6));
        double r1 = fabs(acc[2] / (acc[3] + 1e-6));
        out[0] = (float)(2.0 - r0 - r1);
    }
}

extern "C" void kernel_launch(void* const* d_in, const int* in_sizes, int n_in,
                              void* d_out, int out_size, void* d_ws, size_t ws_size,
                              hipStream_t stream) {
    const float* labels = (const float*)d_in[0];
    const float* inputs = (const float*)d_in[1];
    float* out = (float*)d_out;

    // ws layout:
    //   [0)       pS : 2048*3 doubles = 49152 B
    //   [192128)  pZ : 1600*4 doubles = 51200 B  (ends 243328)
    double* pS = (double*)d_ws;
    double* pZ = (double*)((char*)d_ws + 192128);

    hipLaunchKernelGGL(sums_kernel, dim3(NBLK_S), dim3(256), 0, stream,
                       labels, inputs, pS);
    hipLaunchKernelGGL(fused_conv_kernel, dim3(NBLK_F), dim3(256), 0, stream,
                       labels, inputs, pS, pZ);
    hipLaunchKernelGGL(finalize_kernel, dim3(1), dim3(256), 0, stream, pZ, out);
}

// Round 9
// 325.321 us; speedup vs baseline: 1.2099x; 1.2099x over previous
//
#include <hip/hip_runtime.h>
#include <math.h>

#define NX   160
#define N2   25600        // 160*160
#define N3   4096000      // 160^3
#define NB   4

#define NBLK_S 2048       // sums kernel: 512 blocks per batch
#define SBLK_PER_B 512
#define F4_PER_BLK 2000   // 1024000 float4 per batch / 512 blocks

#define XT   8            // f4 columns per fused tile (32 x)
#define YT   32           // y rows per fused tile
#define ZCH  10           // z outputs per block (half an XCD slab)
#define SROWS 40          // YT + 8 (y halo)
#define NBLK_F 1600       // 8 xcd * (5 xt * 5 yt * 2 zs * 4 b)

// 1D Gaussian taps exp(-d^2/50), d=-4..4 (NOT normalized, matches reference)
__device__ __constant__ float G1[9] = {
    0.72614903f, 0.83527021f, 0.92311635f, 0.98019867f, 1.0f,
    0.98019867f, 0.92311635f, 0.83527021f, 0.72614903f};

// edge sums: FULL - missing taps at low/high boundary
#define ES_FULL 7.92946852f
__device__ __constant__ float ES_M[4] = {3.46473426f, 2.48453559f, 1.56141924f,
                                         0.72614903f};
__device__ inline float edge_sum(int i) {
    float s = ES_FULL;
    if (i < 4) s -= ES_M[i];
    if (i > NX - 5) s -= ES_M[NX - 1 - i];
    return s;
}

__device__ inline float4 f4_zero() { return make_float4(0.f, 0.f, 0.f, 0.f); }
__device__ inline float4 f4_axpy(float a, float4 b, float4 c) {
    return make_float4(c.x + a * b.x, c.y + a * b.y, c.z + a * b.z, c.w + a * b.w);
}

// block = 256 threads (4 waves). Reduce NV doubles, plain store.
template <int NV>
__device__ inline void block_reduce_store(double* vals, double* dst) {
    __shared__ double red[4][NV];
    int lane = threadIdx.x & 63;
    int wave = threadIdx.x >> 6;
#pragma unroll
    for (int v = 0; v < NV; ++v) {
        double x = vals[v];
#pragma unroll
        for (int off = 32; off > 0; off >>= 1) x += __shfl_down(x, off, 64);
        if (lane == 0) red[wave][v] = x;
    }
    __syncthreads();
    if (threadIdx.x < NV) {
        int v = threadIdx.x;
        dst[v] = red[0][v] + red[1][v] + red[2][v] + red[3][v];
    }
}

// Pure streaming per-batch sums (verified R7). Coalesced float4.
__global__ __launch_bounds__(256) void sums_kernel(
    const float* __restrict__ labels, const float* __restrict__ inputs,
    double* __restrict__ pS) {
    int blk = blockIdx.x;
    int b = blk >> 9;          // 0..3
    int chunk = blk & 511;
    const float4* lp = (const float4*)(labels + b * N3) + chunk * F4_PER_BLK;
    const float4* ip = (const float4*)(inputs + b * N3) + chunk * F4_PER_BLK;
    double sp = 0.0, sip = 0.0, si = 0.0;
    for (int i = threadIdx.x; i < F4_PER_BLK; i += 256) {
        float4 p = lp[i];
        float4 in = ip[i];
        sp += (double)(p.x + p.y + p.z + p.w);
        sip += (double)(in.x * p.x + in.y * p.y + in.z * p.z + in.w * p.w);
        si += (double)(in.x + in.y + in.z + in.w);
    }
    double vals[3] = {sp, sip, si};
    block_reduce_store<3>(vals, pS + 3 * blk);
}

// x-conv of 4 outputs at f4-col gc of row (12 inputs -> 4 outputs)
__device__ inline float4 xconv_row(const float* __restrict__ row, int gc) {
    float w[12];
#pragma unroll
    for (int c = 0; c < 3; ++c) {
        int g4 = gc - 1 + c;
        float4 v = (g4 >= 0 && g4 < 40) ? *(const float4*)&row[4 * g4]
                                        : f4_zero();
        w[4 * c] = v.x; w[4 * c + 1] = v.y;
        w[4 * c + 2] = v.z; w[4 * c + 3] = v.w;
    }
    float4 o = f4_zero();
#pragma unroll
    for (int kk = 0; kk < 9; ++kk) {
        float g = G1[kk];
        o.x += g * w[kk];     o.y += g * w[kk + 1];
        o.z += g * w[kk + 2]; o.w += g * w[kk + 3];
    }
    return o;
}

// stage x-conv of plane zp (tile rows y0-4 .. y0+YT+3) into dst (SROWS x XT)
__device__ inline void stage_plane(const float* __restrict__ lbase, int zp,
                                   int y0, int x0f, int tid, float4* dst) {
    if (zp >= 0 && zp < NX) {
        const float* pl = lbase + zp * N2;
#pragma unroll
        for (int s0 = 0; s0 < SROWS * XT; s0 += 256) {
            int s = s0 + tid;
            if (s < SROWS * XT) {
                int sc = s & 7;           // f4 col in tile
                int sr = s >> 3;          // staged row
                int gy = y0 - 4 + sr;
                float4 o = f4_zero();
                if (gy >= 0 && gy < NX) o = xconv_row(pl + gy * NX, x0f + sc);
                dst[s] = o;
            }
        }
    } else {
#pragma unroll
        for (int s0 = 0; s0 < SROWS * XT; s0 += 256) {
            int s = s0 + tid;
            if (s < SROWS * XT) dst[s] = f4_zero();
        }
    }
}

__device__ inline float4 ydot9(const float4 (*sb)[XT], int oy, int ox) {
    float4 w8 = f4_zero();
#pragma unroll
    for (int dy = 0; dy < 9; ++dy) w8 = f4_axpy(G1[dy], sb[oy + dy][ox], w8);
    return w8;
}

// R12: R11 structure with the scratch-spill fixed — win[] is ONLY ever
// indexed by compile-time constants (unrolled prologue k=0..7, static
// shift in main loop). Rule: runtime-indexed reg arrays -> local memory
// (R8: 504MB scratch WRITE, 260us).
__global__ __launch_bounds__(256) void fused_conv_kernel(
    const float* __restrict__ labels, const float* __restrict__ inputs,
    const double* __restrict__ pS, double* __restrict__ pZ) {
    int tid = threadIdx.x;
    int xcd = blockIdx.x & 7;
    int u = blockIdx.x >> 3;      // 0..199
    int xt = u % 5;
    int yt = (u / 5) % 5;
    int zs = (u / 25) % 2;
    int b = u / 50;               // 0..3, uniform per block
    int x0f = xt * XT;            // f4 col base
    int y0 = yt * YT;
    int z0 = xcd * 20 + zs * ZCH;

    // ---- fused S reduce (verified R7/R10 pattern) ----
    __shared__ float sM[2];
    {
        double v0 = 0, v1 = 0, v2 = 0;
        for (int i = tid; i < SBLK_PER_B; i += 256) {
            const double* p = pS + 3 * (SBLK_PER_B * b + i);
            v0 += p[0]; v1 += p[1]; v2 += p[2];
        }
        __shared__ double red[4][3];
        int lane = tid & 63, wave = tid >> 6;
        double vals[3] = {v0, v1, v2};
#pragma unroll
        for (int v = 0; v < 3; ++v) {
            double x = vals[v];
#pragma unroll
            for (int off = 32; off > 0; off >>= 1) x += __shfl_down(x, off, 64);
            if (lane == 0) red[wave][v] = x;
        }
        __syncthreads();
        if (tid == 0) {
            double sp = red[0][0] + red[1][0] + red[2][0] + red[3][0];
            double sip = red[0][1] + red[1][1] + red[2][1] + red[3][1];
            double si = red[0][2] + red[1][2] + red[2][2] + red[3][2];
            const double Nv = (double)N3;
            sM[0] = (float)((sip / Nv) / (sp / Nv + 1e-5));
            sM[1] = (float)(((si - sip) / Nv) / ((Nv - sp) / Nv + 1e-5));
        }
        __syncthreads();
    }
    float m0 = sM[0], m1 = sM[1];

    // output coords for this thread
    int ox = tid & 7;             // f4 col within tile
    int oy = tid >> 3;            // y row within tile, 0..31
    int y = y0 + oy;
    int xo = (x0f + ox) * 4;
    float ey = edge_sum(y);
    float cx[4] = {edge_sum(xo) * ey, edge_sum(xo + 1) * ey,
                   edge_sum(xo + 2) * ey, edge_sum(xo + 3) * ey};

    const float* lbase = labels + b * N3;
    const float* ibase = inputs + b * N3;
    int po = y * NX + xo;         // in-plane offset of this thread's output

    __shared__ float4 sbuf[2][SROWS][XT];

    float4 win[9];
    // prologue: planes z0-4 .. z0+3 -> win[0..7], k compile-time
#pragma unroll
    for (int k = 0; k < 8; ++k) {
        stage_plane(lbase, z0 - 4 + k, y0, x0f, tid, &sbuf[k & 1][0][0]);
        __syncthreads();
        win[k] = ydot9(sbuf[k & 1], oy, ox);
        __syncthreads();
    }

    float n0 = 0.f, d0 = 0.f, n1 = 0.f, d1 = 0.f;
    for (int k = 8; k < ZCH + 8; ++k) {
        stage_plane(lbase, z0 - 4 + k, y0, x0f, tid, &sbuf[k & 1][0][0]);
        __syncthreads();
        float4 w8 = ydot9(sbuf[k & 1], oy, ox);
        if (k > 8) {   // static indices inside; runtime guard is fine
#pragma unroll
            for (int d = 0; d < 8; ++d) win[d] = win[d + 1];
        }
        win[8] = w8;

        int z = z0 + k - 8;
        float4 pv = *(const float4*)&lbase[z * N2 + po];
        float4 iv = *(const float4*)&ibase[z * N2 + po];
        float4 c4 = f4_zero();
#pragma unroll
        for (int d = 0; d < 9; ++d) c4 = f4_axpy(G1[d], win[d], c4);
        float ez = edge_sum(z);
        float pc[4] = {pv.x, pv.y, pv.z, pv.w};
        float ic[4] = {iv.x, iv.y, iv.z, iv.w};
        float cc[4] = {c4.x, c4.y, c4.z, c4.w};
#pragma unroll
        for (int l = 0; l < 4; ++l) {
            float c1 = cx[l] * ez - cc[l];  // conv(1-p) via conv(ones)
            float df0 = ic[l] - m0; df0 *= df0;
            float w0 = __expf(-df0 * df0);
            float df1 = ic[l] - m1; df1 *= df1;
            float w1 = __expf(-df1 * df1);
            n0 += cc[l] * pc[l] * w0;
            d0 += cc[l] * w0;
            n1 += c1 * (1.f - pc[l]) * w1;
            d1 += c1 * w1;
        }
        __syncthreads();   // protect sbuf[k&1] reuse at iter k+2
    }
    double vals[4] = {(double)n0, (double)d0, (double)n1, (double)d1};
    block_reduce_store<4>(vals, pZ + 4 * blockIdx.x);
}

// single block: sum 1600 per-block partials, compute final loss
__global__ __launch_bounds__(256) void finalize_kernel(
    const double* __restrict__ pZ, float* __restrict__ out) {
    double a0 = 0, a1 = 0, a2 = 0, a3 = 0;
    for (int i = threadIdx.x; i < NBLK_F; i += 256) {
        const double* p = &pZ[4 * i];
        a0 += p[0]; a1 += p[1]; a2 += p[2]; a3 += p[3];
    }
    __shared__ double red[4][4];
    int lane = threadIdx.x & 63;
    int wave = threadIdx.x >> 6;
    double vals[4] = {a0, a1, a2, a3};
#pragma unroll
    for (int v = 0; v < 4; ++v) {
        double x = vals[v];
#pragma unroll
        for (int off = 32; off > 0; off >>= 1) x += __shfl_down(x, off, 64);
        if (lane == 0) red[wave][v] = x;
    }
    __syncthreads();
    if (threadIdx.x == 0) {
        double acc[4];
#pragma unroll
        for (int v = 0; v < 4; ++v)
            acc[v] = red[0][v] + red[1][v] + red[2][v] + red[3][v];
        double r0 = fabs(acc[0] / (acc[1] + 1e-6));
        double r1 = fabs(acc[2] / (acc[3] + 1e-6));
        out[0] = (float)(2.0 - r0 - r1);
    }
}

extern "C" void kernel_launch(void* const* d_in, const int* in_sizes, int n_in,
                              void* d_out, int out_size, void* d_ws, size_t ws_size,
                              hipStream_t stream) {
    const float* labels = (const float*)d_in[0];
    const float* inputs = (const float*)d_in[1];
    float* out = (float*)d_out;

    // ws layout:
    //   [0)       pS : 2048*3 doubles = 49152 B
    //   [192128)  pZ : 1600*4 doubles = 51200 B  (ends 243328)
    double* pS = (double*)d_ws;
    double* pZ = (double*)((char*)d_ws + 192128);

    hipLaunchKernelGGL(sums_kernel, dim3(NBLK_S), dim3(256), 0, stream,
                       labels, inputs, pS);
    hipLaunchKernelGGL(fused_conv_kernel, dim3(NBLK_F), dim3(256), 0, stream,
                       labels, inputs, pS, pZ);
    hipLaunchKernelGGL(finalize_kernel, dim3(1), dim3(256), 0, stream, pZ, out);
}

// Round 10
// 243.494 us; speedup vs baseline: 1.6165x; 1.3361x over previous
//
#include <hip/hip_runtime.h>
#include <math.h>

#define NX   160
#define N2   25600        // 160*160
#define N3   4096000      // 160^3
#define NB   4

#define NBLK_S 2048       // sums kernel: 512 blocks per batch
#define SBLK_PER_B 512
#define F4_PER_BLK 2000   // 1024000 float4 per batch / 512 blocks

#define XT   8            // f4 columns per fused tile (32 x)
#define XTP  10           // padded row stride in f4 (2-way banks max)
#define YT   32           // y rows per fused tile
#define ZCH  20           // z outputs per block (full XCD slab)
#define SROWS 40          // YT + 8 (y halo)
#define NBLK_F 800        // 8 xcd * (5 xt * 5 yt * 4 b)

// 1D Gaussian taps exp(-d^2/50), d=-4..4 (NOT normalized, matches reference)
__device__ __constant__ float G1[9] = {
    0.72614903f, 0.83527021f, 0.92311635f, 0.98019867f, 1.0f,
    0.98019867f, 0.92311635f, 0.83527021f, 0.72614903f};

// edge sums: FULL - missing taps at low/high boundary
#define ES_FULL 7.92946852f
__device__ __constant__ float ES_M[4] = {3.46473426f, 2.48453559f, 1.56141924f,
                                         0.72614903f};
__device__ inline float edge_sum(int i) {
    float s = ES_FULL;
    if (i < 4) s -= ES_M[i];
    if (i > NX - 5) s -= ES_M[NX - 1 - i];
    return s;
}

__device__ inline float4 f4_zero() { return make_float4(0.f, 0.f, 0.f, 0.f); }
__device__ inline float4 f4_axpy(float a, float4 b, float4 c) {
    return make_float4(c.x + a * b.x, c.y + a * b.y, c.z + a * b.z, c.w + a * b.w);
}

// block = 256 threads (4 waves). Reduce NV doubles, plain store.
template <int NV>
__device__ inline void block_reduce_store(double* vals, double* dst) {
    __shared__ double red[4][NV];
    int lane = threadIdx.x & 63;
    int wave = threadIdx.x >> 6;
#pragma unroll
    for (int v = 0; v < NV; ++v) {
        double x = vals[v];
#pragma unroll
        for (int off = 32; off > 0; off >>= 1) x += __shfl_down(x, off, 64);
        if (lane == 0) red[wave][v] = x;
    }
    __syncthreads();
    if (threadIdx.x < NV) {
        int v = threadIdx.x;
        dst[v] = red[0][v] + red[1][v] + red[2][v] + red[3][v];
    }
}

// Pure streaming per-batch sums (verified R7). Coalesced float4.
__global__ __launch_bounds__(256) void sums_kernel(
    const float* __restrict__ labels, const float* __restrict__ inputs,
    double* __restrict__ pS) {
    int blk = blockIdx.x;
    int b = blk >> 9;          // 0..3
    int chunk = blk & 511;
    const float4* lp = (const float4*)(labels + b * N3) + chunk * F4_PER_BLK;
    const float4* ip = (const float4*)(inputs + b * N3) + chunk * F4_PER_BLK;
    double sp = 0.0, sip = 0.0, si = 0.0;
    for (int i = threadIdx.x; i < F4_PER_BLK; i += 256) {
        float4 p = lp[i];
        float4 in = ip[i];
        sp += (double)(p.x + p.y + p.z + p.w);
        sip += (double)(in.x * p.x + in.y * p.y + in.z * p.z + in.w * p.w);
        si += (double)(in.x + in.y + in.z + in.w);
    }
    double vals[3] = {sp, sip, si};
    block_reduce_store<3>(vals, pS + 3 * blk);
}

// raw 12-float row segment (3 guarded float4) for staged row (gy, f4-col gc)
__device__ inline void load_row_raw(const float* __restrict__ lbase, int zp,
                                    int gy, int gc, float4* r) {
    bool ok = (zp >= 0) && (zp < NX) && (gy >= 0) && (gy < NX);
    const float* row = lbase + zp * N2 + gy * NX;
#pragma unroll
    for (int c = 0; c < 3; ++c) {
        int g4 = gc - 1 + c;
        r[c] = (ok && g4 >= 0 && g4 < 40) ? *(const float4*)&row[4 * g4]
                                          : f4_zero();
    }
}

// x-conv: 12 raw floats (3 f4) -> 4 outputs
__device__ inline float4 xconv_regs(const float4* r) {
    float w[12] = {r[0].x, r[0].y, r[0].z, r[0].w, r[1].x, r[1].y,
                   r[1].z, r[1].w, r[2].x, r[2].y, r[2].z, r[2].w};
    float4 o = f4_zero();
#pragma unroll
    for (int kk = 0; kk < 9; ++kk) {
        float g = G1[kk];
        o.x += g * w[kk];     o.y += g * w[kk + 1];
        o.z += g * w[kk + 2]; o.w += g * w[kk + 3];
    }
    return o;
}

__device__ inline float4 ydot9(const float4 (*sb)[XTP], int oy, int ox) {
    float4 w8 = f4_zero();
#pragma unroll
    for (int dy = 0; dy < 9; ++dy) w8 = f4_axpy(G1[dy], sb[oy + dy][ox], w8);
    return w8;
}

// R13: latency-restructured fused conv.
//  - single rolling loop (no unrolled prologue): win[] shift fully static.
//  - launch_bounds(256,4): VGPR<=128 -> 4 blocks/CU (R12: 180 VGPR, 2/CU, 10% occ).
//  - T14 async stage: raw rows of plane k+1 -> regs at iter TOP; xconv in regs;
//    ONE barrier per iter at END (WAR safe: overwritten buffer's reads all
//    precede the previous end-barrier; RAW safe: writes precede end-barrier).
//  - LDS rows padded to XTP=10 f4 -> read/write bank windows 2-way max (free).
// Slab-mapped: xcd = bid&7 owns z in [20*xcd, 20*xcd+20).
__global__ __launch_bounds__(256, 4) void fused_conv_kernel(
    const float* __restrict__ labels, const float* __restrict__ inputs,
    const double* __restrict__ pS, double* __restrict__ pZ) {
    int tid = threadIdx.x;
    int xcd = blockIdx.x & 7;
    int u = blockIdx.x >> 3;      // 0..99
    int xt = u % 5;
    int yt = (u / 5) % 5;
    int b = u / 25;               // 0..3, uniform per block
    int x0f = xt * XT;            // f4 col base
    int y0 = yt * YT;
    int z0 = xcd * 20;

    // ---- fused S reduce (verified pattern) ----
    __shared__ float sM[2];
    {
        double v0 = 0, v1 = 0, v2 = 0;
        for (int i = tid; i < SBLK_PER_B; i += 256) {
            const double* p = pS + 3 * (SBLK_PER_B * b + i);
            v0 += p[0]; v1 += p[1]; v2 += p[2];
        }
        __shared__ double red[4][3];
        int lane = tid & 63, wave = tid >> 6;
        double vals[3] = {v0, v1, v2};
#pragma unroll
        for (int v = 0; v < 3; ++v) {
            double x = vals[v];
#pragma unroll
            for (int off = 32; off > 0; off >>= 1) x += __shfl_down(x, off, 64);
            if (lane == 0) red[wave][v] = x;
        }
        __syncthreads();
        if (tid == 0) {
            double sp = red[0][0] + red[1][0] + red[2][0] + red[3][0];
            double sip = red[0][1] + red[1][1] + red[2][1] + red[3][1];
            double si = red[0][2] + red[1][2] + red[2][2] + red[3][2];
            const double Nv = (double)N3;
            sM[0] = (float)((sip / Nv) / (sp / Nv + 1e-5));
            sM[1] = (float)(((si - sip) / Nv) / ((Nv - sp) / Nv + 1e-5));
        }
        __syncthreads();
    }
    float m0 = sM[0], m1 = sM[1];

    // output coords
    int ox = tid & 7;             // f4 col within tile
    int oy = tid >> 3;            // y row within tile, 0..31
    int y = y0 + oy;
    int xo = (x0f + ox) * 4;
    float ey = edge_sum(y);
    float cx[4] = {edge_sum(xo) * ey, edge_sum(xo + 1) * ey,
                   edge_sum(xo + 2) * ey, edge_sum(xo + 3) * ey};

    const float* lbase = labels + b * N3;
    const float* ibase = inputs + b * N3;
    int po = y * NX + xo;

    // staged-row assignment: s = tid (all), s2 = tid + 256 (wave 0 only)
    int sra = tid >> 3, sca = tid & 7;          // row 0..31
    int srb = 32 + (tid >> 3), scb = tid & 7;   // row 32..39
    bool hasb = (tid < 64);
    int gya = y0 - 4 + sra, gyb = y0 - 4 + srb;
    int gca = x0f + sca, gcb = x0f + scb;

    __shared__ float4 sbuf[2][SROWS][XTP];

    // stage plane z0-4 into sbuf[0]
    {
        float4 ra[3], rb[3];
        load_row_raw(lbase, z0 - 4, gya, gca, ra);
        if (hasb) load_row_raw(lbase, z0 - 4, gyb, gcb, rb);
        sbuf[0][sra][sca] = xconv_regs(ra);
        if (hasb) sbuf[0][srb][scb] = xconv_regs(rb);
    }
    __syncthreads();

    float4 win[9];
#pragma unroll
    for (int d = 0; d < 9; ++d) win[d] = f4_zero();

    float n0 = 0.f, d0 = 0.f, n1 = 0.f, d1 = 0.f;
    for (int k = 0; k < ZCH + 8; ++k) {
        int cur = k & 1, nxt = cur ^ 1;
        int zstage = z0 - 4 + k + 1;

        // 1. issue raw loads for plane k+1 (latency hides under 3-6)
        float4 ra[3], rb[3];
        load_row_raw(lbase, zstage, gya, gca, ra);
        if (hasb) load_row_raw(lbase, zstage, gyb, gcb, rb);

        // 2. center loads for output iter (issued early)
        int z = z0 + k - 8;
        float4 pv = f4_zero(), iv = f4_zero();
        if (k >= 8) {
            pv = *(const float4*)&lbase[z * N2 + po];
            iv = *(const float4*)&ibase[z * N2 + po];
        }

        // 3. y-dot of plane k from LDS
        float4 w8 = ydot9(sbuf[cur], oy, ox);

        // 4. static window shift
#pragma unroll
        for (int d = 0; d < 8; ++d) win[d] = win[d + 1];
        win[8] = w8;

        // 5. pointwise accumulate
        if (k >= 8) {
            float4 c4 = f4_zero();
#pragma unroll
            for (int d = 0; d < 9; ++d) c4 = f4_axpy(G1[d], win[d], c4);
            float ez = edge_sum(z);
            float pc[4] = {pv.x, pv.y, pv.z, pv.w};
            float ic[4] = {iv.x, iv.y, iv.z, iv.w};
            float cc[4] = {c4.x, c4.y, c4.z, c4.w};
#pragma unroll
            for (int l = 0; l < 4; ++l) {
                float c1 = cx[l] * ez - cc[l];  // conv(1-p) via conv(ones)
                float df0 = ic[l] - m0; df0 *= df0;
                float w0 = __expf(-df0 * df0);
                float df1 = ic[l] - m1; df1 *= df1;
                float w1 = __expf(-df1 * df1);
                n0 += cc[l] * pc[l] * w0;
                d0 += cc[l] * w0;
                n1 += c1 * (1.f - pc[l]) * w1;
                d1 += c1 * w1;
            }
        }

        // 6. xconv in regs, write plane k+1 to sbuf[nxt]
        float4 oa = xconv_regs(ra);
        sbuf[nxt][sra][sca] = oa;
        if (hasb) {
            float4 ob = xconv_regs(rb);
            sbuf[nxt][srb][scb] = ob;
        }

        // 7. single end barrier: RAW for next iter's ydot; WAR covered by
        //    the previous end barrier (reads of old sbuf[nxt] precede it).
        __syncthreads();
    }
    double vals[4] = {(double)n0, (double)d0, (double)n1, (double)d1};
    block_reduce_store<4>(vals, pZ + 4 * blockIdx.x);
}

// single block: sum 800 per-block partials, compute final loss
__global__ __launch_bounds__(256) void finalize_kernel(
    const double* __restrict__ pZ, float* __restrict__ out) {
    double a0 = 0, a1 = 0, a2 = 0, a3 = 0;
    for (int i = threadIdx.x; i < NBLK_F; i += 256) {
        const double* p = &pZ[4 * i];
        a0 += p[0]; a1 += p[1]; a2 += p[2]; a3 += p[3];
    }
    __shared__ double red[4][4];
    int lane = threadIdx.x & 63;
    int wave = threadIdx.x >> 6;
    double vals[4] = {a0, a1, a2, a3};
#pragma unroll
    for (int v = 0; v < 4; ++v) {
        double x = vals[v];
#pragma unroll
        for (int off = 32; off > 0; off >>= 1) x += __shfl_down(x, off, 64);
        if (lane == 0) red[wave][v] = x;
    }
    __syncthreads();
    if (threadIdx.x == 0) {
        double acc[4];
#pragma unroll
        for (int v = 0; v < 4; ++v)
            acc[v] = red[0][v] + red[1][v] + red[2][v] + red[3][v];
        double r0 = fabs(acc[0] / (acc[1] + 1e-6));
        double r1 = fabs(acc[2] / (acc[3] + 1e-6));
        out[0] = (float)(2.0 - r0 - r1);
    }
}

extern "C" void kernel_launch(void* const* d_in, const int* in_sizes, int n_in,
                              void* d_out, int out_size, void* d_ws, size_t ws_size,
                              hipStream_t stream) {
    const float* labels = (const float*)d_in[0];
    const float* inputs = (const float*)d_in[1];
    float* out = (float*)d_out;

    // ws layout:
    //   [0)       pS : 2048*3 doubles = 49152 B
    //   [192128)  pZ : 800*4 doubles = 25600 B  (ends 217728)
    double* pS = (double*)d_ws;
    double* pZ = (double*)((char*)d_ws + 192128);

    hipLaunchKernelGGL(sums_kernel, dim3(NBLK_S), dim3(256), 0, stream,
                       labels, inputs, pS);
    hipLaunchKernelGGL(fused_conv_kernel, dim3(NBLK_F), dim3(256), 0, stream,
                       labels, inputs, pS, pZ);
    hipLaunchKernelGGL(finalize_kernel, dim3(1), dim3(256), 0, stream, pZ, out);
}